// Round 10
// baseline (354.858 us; speedup 1.0000x reference)
//
#include <hip/hip_runtime.h>

// LengthAdaptor: B=16, T=512, C_IN=512, C_HID=256, C_EMB=384, K=5, MAX_DUR=8
// Outputs (concat, f32): x_up [16,4096,512] | ldp [16,512] | emb_up [16,4096,384]
//
// R10: 4 dispatches.
//  D1 prep: weight swizzle + duration scan/idx.
//  D2 conv1 (blk%3==0) + x_up gather, interleaved, 3 blocks/CU.
//  D3 conv2 with LN1 computed IN-BLOCK during staging (reads conv1's f32
//     pre-activation hraw, applies bias+lrelu+LN, bf16 -> LDS) + emb_up
//     gather. Kills the ln1 dispatch and the h1 buffer.
//  D4 ln2: bias+lrelu+LN+linear+mask -> ldp.
// Conv core: 32x32x16 MFMA, fragment-contiguous B from L2, XOR-swizzled LDS A.

constexpr int Bn = 16, Tn = 512, CIN1 = 512, CHID = 256, CEMB = 384, MAXMEL = 4096;
constexpr int NROWS = Bn * Tn;
#define LRELU 0.3f
#define EPSV 1e-5f

typedef __attribute__((ext_vector_type(8))) short bf16x8;
typedef __attribute__((ext_vector_type(4))) float f32x4;
typedef __attribute__((ext_vector_type(16))) float f32x16;
typedef __attribute__((ext_vector_type(4))) unsigned int u32x4;
typedef unsigned short ushort_t;

static __device__ __forceinline__ ushort_t f2bf(float f) {
  unsigned u = __builtin_bit_cast(unsigned, f);
  unsigned r = (u + 0x7fffu + ((u >> 16) & 1u)) >> 16;  // RNE
  return (ushort_t)r;
}

// ---------------------------------------------------------------------------
// conv1 body: 32x32x16 MFMA, tile 32x128, CI=512 staged in 128-ci chunks.
// ---------------------------------------------------------------------------
static __device__ __forceinline__ void conv1_body(
    int mt, int ns, const float* __restrict__ xin,
    const ushort_t* __restrict__ wB, float* __restrict__ hraw) {
  constexpr int CI = 512;
  constexpr int ROWS = 36, LDSTRIDE = 136;
  __shared__ ushort_t sA[ROWS * LDSTRIDE];

  const int b = mt >> 4, t0 = (mt & 15) * 32;
  const int tid = threadIdx.x;
  const int l = tid & 63, nh = tid >> 6;
  const int lm = l & 31, lq = l >> 5;
  const int cob32 = ns * 4 + nh;

  f32x16 acc;
#pragma unroll
  for (int i = 0; i < 16; ++i) acc[i] = 0.f;

  const ushort_t* pB = wB + (size_t)cob32 * 512 + l * 8;

#pragma unroll 1
  for (int chunk = 0; chunk < 4; ++chunk) {
    {
      const int cibase = chunk * 128;
#pragma unroll 1
      for (int i = 0; i < 9; ++i) {
        const int p = i * 256 + tid;      // 2304 = 36*64
        const int r = p >> 6, c2 = (p & 63) * 2;
        const int t = t0 - 2 + r;
        unsigned hv = 0;
        if ((unsigned)t < (unsigned)Tn) {
          const float2 v = *(const float2*)(xin + (size_t)(b * Tn + t) * CI + cibase + c2);
          hv = (unsigned)f2bf(v.x) | ((unsigned)f2bf(v.y) << 16);
        }
        const int sw = ((r >> 3) & 3) << 3;
        *(unsigned*)&sA[r * LDSTRIDE + (c2 ^ sw)] = hv;
      }
    }
    __syncthreads();

#pragma unroll 1
    for (int ksh = 0; ksh < 5; ++ksh) {
      const int r = lm + ksh;
      const int sw = ((r >> 3) & 3) << 3;
      const size_t bbase = (size_t)((ksh * (CI / 16) + chunk * 8) * 8) * 512;
#pragma unroll
      for (int kk = 0; kk < 8; ++kk) {
        const int c = (kk * 16 + lq * 8) ^ sw;
        const bf16x8 a = *(const bf16x8*)&sA[r * LDSTRIDE + c];
        const bf16x8 bv = *(const bf16x8*)(pB + bbase + (size_t)kk * 8 * 512);
        acc = __builtin_amdgcn_mfma_f32_32x32x16_bf16(a, bv, acc, 0, 0, 0);
      }
    }
    __syncthreads();
  }

  const int col = ns * 128 + nh * 32 + lm;
  float* pOut = hraw + (size_t)(b * Tn + t0) * 256 + col;
#pragma unroll
  for (int reg = 0; reg < 16; ++reg) {
    const int row = (reg & 3) + 8 * (reg >> 2) + 4 * lq;
    pOut[(size_t)row * 256] = acc[reg];
  }
}

// ---------------------------------------------------------------------------
// Dispatch 2: conv1 (blk%3==0, 512) + x_up gather (1024). Grid 1536.
// ---------------------------------------------------------------------------
__global__ __launch_bounds__(256, 3) void conv1_gather_kernel(
    const float* __restrict__ x_res, const ushort_t* __restrict__ w1,
    float* __restrict__ hraw,
    const float* __restrict__ x, const int* __restrict__ idx,
    float* __restrict__ x_up) {
  const int blk = blockIdx.x;
  if (blk % 3 == 0) {
    const int cid = blk / 3;
    conv1_body(cid & 255, cid >> 8, x_res, w1, hraw);
    return;
  }
  const int gid = blk - 1 - blk / 3;      // 0..1023
  const f32x4* x4 = (const f32x4*)x;
  f32x4* xu4 = (f32x4*)x_up;
  const int tid0 = gid * 256 + threadIdx.x;
  const int stride = 1024 * 256;
  const f32x4 z = (f32x4){0.f, 0.f, 0.f, 0.f};
  for (int u = tid0; u < Bn * MAXMEL * 128; u += stride) {
    const int bp = u >> 7, i = u & 127;
    const int t = idx[bp];
    const int b = bp >> 12;
    const f32x4 v = (t >= 0) ? x4[((b << 9) + t) * 128 + i] : z;
    __builtin_nontemporal_store(v, &xu4[u]);
  }
}

// ---------------------------------------------------------------------------
// Dispatch 3: conv2 with in-block LN1 staging (blk%3==0) + emb_up gather.
// conv2 block: stage 36 rows of hraw (f32 pre-act layer1), apply c1b +
// lrelu + LN(g1,b1) per row, bf16 -> swizzled sA; then 80 MFMAs over CI=256.
// ---------------------------------------------------------------------------
__global__ __launch_bounds__(256, 3) void conv2_gather_kernel(
    const float* __restrict__ hraw,       // [8192][256] layer1 pre-act
    const ushort_t* __restrict__ w2,
    const float* __restrict__ c1b, const float* __restrict__ g1,
    const float* __restrict__ b1, float* __restrict__ hraw2,
    const float* __restrict__ emb, const int* __restrict__ idx,
    float* __restrict__ emb_up) {
  constexpr int CI = 256;
  constexpr int ROWS = 36, LDSTRIDE = 264;
  __shared__ ushort_t sA[ROWS * LDSTRIDE];          // 19.0 KB
  __shared__ float sps[ROWS * 64], spq[ROWS * 64];  // 18.4 KB
  __shared__ float sq1[ROWS * 4], sq2[ROWS * 4];
  __shared__ float smu[ROWS], srs[ROWS];

  const int blk = blockIdx.x;
  if (blk % 3 != 0) {
    const int gid = blk - 1 - blk / 3;
    const f32x4* e4 = (const f32x4*)emb;
    f32x4* eu4 = (f32x4*)emb_up;
    const int tid0 = gid * 256 + threadIdx.x;
    const int stride = 1024 * 256;
    const f32x4 z = (f32x4){0.f, 0.f, 0.f, 0.f};
    for (int u = tid0; u < Bn * MAXMEL * 96; u += stride) {
      const int bp = u / 96, i = u - bp * 96;
      const int t = idx[bp];
      const int b = bp >> 12;
      const f32x4 v = (t >= 0) ? e4[((b << 9) + t) * 96 + i] : z;
      __builtin_nontemporal_store(v, &eu4[u]);
    }
    return;
  }

  const int cid = blk / 3;
  const int mt = cid & 255, ns = cid >> 8;
  const int b = mt >> 4, t0 = (mt & 15) * 32;
  const int tid = threadIdx.x;
  const int l = tid & 63, nh = tid >> 6;
  const int lm = l & 31, lq = l >> 5;
  const int cob32 = ns * 4 + nh;

  // ---- phase A: load 36 rows x 256 ch of hraw, bias+lrelu, partial stats ----
  float va[9][4];
#pragma unroll
  for (int i = 0; i < 9; ++i) {
    const int p = i * 256 + tid;          // r = p>>6, seg = p&63
    const int r = p >> 6, seg = p & 63;
    const int t = t0 - 2 + r;
    float s = 0.f, s2 = 0.f;
    if ((unsigned)t < (unsigned)Tn) {
      const f32x4 h4 = *(const f32x4*)(hraw + (size_t)(b * Tn + t) * 256 + seg * 4);
      const f32x4 b4 = *(const f32x4*)(c1b + seg * 4);
#pragma unroll
      for (int q = 0; q < 4; ++q) {
        float v = h4[q] + b4[q];
        v = (v > 0.f) ? v : LRELU * v;
        va[i][q] = v;
        s += v;
        s2 += v * v;
      }
    } else {
      va[i][0] = va[i][1] = va[i][2] = va[i][3] = 0.f;
    }
    sps[r * 64 + seg] = s;
    spq[r * 64 + seg] = s2;
  }
  __syncthreads();

  // ---- phase B: reduce 64 segs -> mu/rs per row ----
  if (tid < 144) {
    const int r = tid >> 2, q = tid & 3;  // r<36, quarter of 16 segs
    float s = 0.f, s2 = 0.f;
#pragma unroll
    for (int j = 0; j < 16; ++j) {
      s += sps[r * 64 + q * 16 + j];
      s2 += spq[r * 64 + q * 16 + j];
    }
    sq1[r * 4 + q] = s;
    sq2[r * 4 + q] = s2;
  }
  __syncthreads();
  if (tid < ROWS) {
    const float s = sq1[tid * 4] + sq1[tid * 4 + 1] + sq1[tid * 4 + 2] + sq1[tid * 4 + 3];
    const float s2 = sq2[tid * 4] + sq2[tid * 4 + 1] + sq2[tid * 4 + 2] + sq2[tid * 4 + 3];
    const float mu = s * (1.f / 256.f);
    const float var = s2 * (1.f / 256.f) - mu * mu;
    smu[tid] = mu;
    srs[tid] = rsqrtf(var + EPSV);
  }
  __syncthreads();

  // ---- phase C: normalize, bf16, swizzled store to sA ----
#pragma unroll
  for (int i = 0; i < 9; ++i) {
    const int p = i * 256 + tid;
    const int r = p >> 6, seg = p & 63;
    const int t = t0 - 2 + r;
    unsigned pk0 = 0, pk1 = 0;
    if ((unsigned)t < (unsigned)Tn) {
      const float mu = smu[r], rs = srs[r];
      const f32x4 g4 = *(const f32x4*)(g1 + seg * 4);
      const f32x4 e4 = *(const f32x4*)(b1 + seg * 4);
      const float h0 = (va[i][0] - mu) * rs * g4[0] + e4[0];
      const float h1 = (va[i][1] - mu) * rs * g4[1] + e4[1];
      const float h2 = (va[i][2] - mu) * rs * g4[2] + e4[2];
      const float h3 = (va[i][3] - mu) * rs * g4[3] + e4[3];
      pk0 = (unsigned)f2bf(h0) | ((unsigned)f2bf(h1) << 16);
      pk1 = (unsigned)f2bf(h2) | ((unsigned)f2bf(h3) << 16);
    }
    const int sw = ((r >> 3) & 3) << 3;
    const int c = (seg * 4) ^ sw;         // sw bits >=8 leave low 3 bits intact
    *(unsigned*)&sA[r * LDSTRIDE + c] = pk0;
    *(unsigned*)&sA[r * LDSTRIDE + c + 2] = pk1;
  }
  __syncthreads();

  // ---- MFMA: 5 ksh x 16 kk over CI=256 ----
  f32x16 acc;
#pragma unroll
  for (int i = 0; i < 16; ++i) acc[i] = 0.f;
  const ushort_t* pB = w2 + (size_t)cob32 * 512 + l * 8;
#pragma unroll 1
  for (int ksh = 0; ksh < 5; ++ksh) {
    const int r = lm + ksh;
    const int sw = ((r >> 3) & 3) << 3;
    const size_t bbase = (size_t)(ksh * (CI / 16) * 8) * 512;
#pragma unroll
    for (int kk = 0; kk < 16; ++kk) {
      const int c = (kk * 16 + lq * 8) ^ sw;
      const bf16x8 a = *(const bf16x8*)&sA[r * LDSTRIDE + c];
      const bf16x8 bv = *(const bf16x8*)(pB + bbase + (size_t)kk * 8 * 512);
      acc = __builtin_amdgcn_mfma_f32_32x32x16_bf16(a, bv, acc, 0, 0, 0);
    }
  }

  const int col = ns * 128 + nh * 32 + lm;
  float* pOut = hraw2 + (size_t)(b * Tn + t0) * 256 + col;
#pragma unroll
  for (int reg = 0; reg < 16; ++reg) {
    const int row = (reg & 3) + 8 * (reg >> 2) + 4 * lq;
    pOut[(size_t)row * 256] = acc[reg];
  }
}

// ---------------------------------------------------------------------------
// Dispatch 4: bias2 + lrelu + LN(g2,b2) + linear + mask -> ldp.
// ---------------------------------------------------------------------------
__global__ __launch_bounds__(256) void ln2_kernel(
    const float* __restrict__ hraw2, const float* __restrict__ bias,
    const float* __restrict__ g, const float* __restrict__ be,
    const float* __restrict__ lw, const float* __restrict__ lb,
    const unsigned char* __restrict__ mask, float* __restrict__ ldp) {
  const int row = blockIdx.x * 4 + (threadIdx.x >> 6);
  const int l = threadIdx.x & 63;
  const f32x4 p = ((const f32x4*)hraw2)[row * 64 + l];
  const f32x4 bi = ((const f32x4*)bias)[l];
  float v0 = p.x + bi.x, v1 = p.y + bi.y, v2 = p.z + bi.z, v3 = p.w + bi.w;
  v0 = (v0 > 0.f) ? v0 : LRELU * v0;
  v1 = (v1 > 0.f) ? v1 : LRELU * v1;
  v2 = (v2 > 0.f) ? v2 : LRELU * v2;
  v3 = (v3 > 0.f) ? v3 : LRELU * v3;
  float s = v0 + v1 + v2 + v3;
  float s2 = v0 * v0 + v1 * v1 + v2 * v2 + v3 * v3;
#pragma unroll
  for (int off = 32; off >= 1; off >>= 1) {
    s += __shfl_xor(s, off);
    s2 += __shfl_xor(s2, off);
  }
  const float mu = s * (1.f / 256.f);
  const float var = s2 * (1.f / 256.f) - mu * mu;
  const float rs = rsqrtf(var + EPSV);
  const f32x4 gg = ((const f32x4*)g)[l];
  const f32x4 bb = ((const f32x4*)be)[l];
  const f32x4 lv = ((const f32x4*)lw)[l];
  float d = ((v0 - mu) * rs * gg.x + bb.x) * lv.x;
  d += ((v1 - mu) * rs * gg.y + bb.y) * lv.y;
  d += ((v2 - mu) * rs * gg.z + bb.z) * lv.z;
  d += ((v3 - mu) * rs * gg.w + bb.w) * lv.w;
#pragma unroll
  for (int off = 32; off >= 1; off >>= 1) d += __shfl_xor(d, off);
  if (l == 0) {
    float val = d + lb[0];
    if (mask[row]) val = 0.f;
    ldp[row] = val;
  }
}

// ---------------------------------------------------------------------------
// Dispatch 1: weight prep (blocks 0..239) + build_idx (blocks 240..255).
// ---------------------------------------------------------------------------
__global__ __launch_bounds__(512) void prep_kernel(
    const float* __restrict__ w1src, const float* __restrict__ w2src,
    ushort_t* __restrict__ w1dst, ushort_t* __restrict__ w2dst,
    const int* __restrict__ dur, int* __restrict__ idx) {
  __shared__ int wsum[8];
  const int blk = blockIdx.x;
  const int tid = threadIdx.x;
  if (blk < 240) {
    const float* src;
    ushort_t* dst;
    int CI, fr, sh;
    const int wv = tid >> 6, l = tid & 63;
    if (blk < 160) { src = w1src; dst = w1dst; CI = 512; sh = 5; fr = blk * 8 + wv; }
    else           { src = w2src; dst = w2dst; CI = 256; sh = 4; fr = (blk - 160) * 8 + wv; }
    const int cob32 = fr & 7;
    const int t = fr >> 3;
    const int ksh = t >> sh;
    const int ci16 = t & ((1 << sh) - 1);
    const int ci = ci16 * 16 + (l >> 5) * 8;
    const int co = cob32 * 32 + (l & 31);
    ushort_t v[8];
#pragma unroll
    for (int j = 0; j < 8; ++j)
      v[j] = f2bf(src[((size_t)(ksh * CI + ci + j)) * 256 + co]);
    u32x4 pack;
#pragma unroll
    for (int q = 0; q < 4; ++q)
      pack[q] = (unsigned)v[q * 2] | ((unsigned)v[q * 2 + 1] << 16);
    *(u32x4*)&dst[(size_t)fr * 512 + l * 8] = pack;
    return;
  }
  const int b = blk - 240;
  const int lane = tid & 63, wv = tid >> 6;
  const int d = dur[b * Tn + tid];
  int v = d;
#pragma unroll
  for (int off = 1; off <= 32; off <<= 1) {
    const int t = __shfl_up(v, off);
    if (lane >= off) v += t;
  }
  if (lane == 63) wsum[wv] = v;
  __syncthreads();
  int woff = 0, total = 0;
#pragma unroll
  for (int i = 0; i < 8; ++i) {
    const int s = wsum[i];
    if (i < wv) woff += s;
    total += s;
  }
  const int end = v + woff;
  for (int p = end - d; p < end; ++p) idx[b * MAXMEL + p] = tid;
  for (int p = total + tid; p < MAXMEL; p += 512) idx[b * MAXMEL + p] = -1;
}

// ---------------------------------------------------------------------------
extern "C" void kernel_launch(void* const* d_in, const int* in_sizes, int n_in,
                              void* d_out, int out_size, void* d_ws, size_t ws_size,
                              hipStream_t stream) {
  const float* x     = (const float*)d_in[0];
  const float* x_res = (const float*)d_in[1];
  const int*   dur   = (const int*)d_in[2];
  const float* emb   = (const float*)d_in[3];
  const unsigned char* mask = (const unsigned char*)d_in[4];
  const float* c1w = (const float*)d_in[5];
  const float* c1b = (const float*)d_in[6];
  const float* g1  = (const float*)d_in[7];
  const float* b1  = (const float*)d_in[8];
  const float* c2w = (const float*)d_in[9];
  const float* c2b = (const float*)d_in[10];
  const float* g2  = (const float*)d_in[11];
  const float* b2  = (const float*)d_in[12];
  const float* lw  = (const float*)d_in[13];
  const float* lb  = (const float*)d_in[14];

  float* x_up   = (float*)d_out;
  float* ldp    = x_up + (size_t)Bn * MAXMEL * CIN1;
  float* emb_up = ldp + (size_t)Bn * Tn;

  // ws: idx 256KB | w1 1.31MB | w2 0.66MB | hraw 8MB | hraw2 8MB ≈ 18.2MB
  int* idx = (int*)d_ws;
  ushort_t* w1 = (ushort_t*)((char*)d_ws + (size_t)Bn * MAXMEL * 4);
  ushort_t* w2 = w1 + (size_t)5 * 512 * 256;
  float* hraw = (float*)(w2 + (size_t)5 * 256 * 256);
  float* hraw2 = hraw + (size_t)NROWS * 256;

  prep_kernel<<<256, 512, 0, stream>>>(c1w, c2w, w1, w2, dur, idx);
  conv1_gather_kernel<<<1536, 256, 0, stream>>>(
      x_res, w1, hraw, x, idx, x_up);
  conv2_gather_kernel<<<1536, 256, 0, stream>>>(
      hraw, w2, c1b, g1, b1, hraw2, emb, idx, emb_up);
  ln2_kernel<<<NROWS / 4, 256, 0, stream>>>(
      hraw2, c2b, g2, b2, lw, lb, mask, ldp);
}